// Round 3
// baseline (491.889 us; speedup 1.0000x reference)
//
#include <hip/hip_runtime.h>

// Problem constants (fixed by the reference file)
#define BATCH   8
#define C_OUT_N 96
#define NK      11
#define C_IN_N  1056      // C_OUT_N * NK
#define GRP     4
#define HOUT    56
#define WOUT    56
#define HIN     60
#define WIN     60
#define EP      2

// Unpadded channel tile: 60 rows x 64-dword stride (cols 0..59 valid).
// OOB shift reads are handled by clamping the address and zeroing the weight,
// so no pad region is needed. 15360 B per buffer, double-buffered = 30720 B.
#define TS      64                // dwords per row (256 B)
#define TROWS   60
#define TILE_DW (TROWS * TS)      // 3840 dwords = 15360 B

#define ROWS_PW 7                 // rows per wave (8 waves x 7 = 56)

// One block per (b, co); 512 threads = 8 waves; double-buffered channels,
// ONE barrier per k. Grid 768 blocks -> 3 blocks/CU -> 24 waves/CU.
__global__ __launch_bounds__(512, 6) void addshift_kernel(
    const float* __restrict__ x,
    const float* __restrict__ w1,
    const float* __restrict__ w2,
    const float* __restrict__ w3,
    const int*   __restrict__ pad_hv,       // (C_IN, 8)
    const int*   __restrict__ idx_identit,  // (C_OUT, 4)
    float* __restrict__ out)                // [out_h | out_v | out_i]
{
    const int co  = blockIdx.x;
    const int b   = blockIdx.y;
    const int tid = threadIdx.x;

    __shared__ __align__(16) float buf[2][TILE_DW];

    const int wave = tid >> 6;
    const int w    = tid & 63;
    const int wc   = (w < WOUT) ? w : (WOUT - 1);   // clamp idle lanes
    const int h0   = wave * ROWS_PW;

    // Block-uniform identity-gather info
    int   kI[GRP];
    float w3v[GRP];
#pragma unroll
    for (int g = 0; g < GRP; ++g) {
        kI[g]  = idx_identit[co * GRP + g] - co * NK;   // in [0, NK)
        w3v[g] = w3[g * C_OUT_N + co];
    }

    float accH[ROWS_PW], accV[ROWS_PW], accI[ROWS_PW];
#pragma unroll
    for (int i = 0; i < ROWS_PW; ++i) { accH[i] = 0.f; accV[i] = 0.f; accI[i] = 0.f; }

    const float* chan_base = x + ((size_t)b * C_IN_N + (size_t)co * NK) * (HIN * WIN);

    // Each channel = 900 float4; 512 threads -> 2 per thread (t=1 partial).
    float4 pre[2];

    // Prologue: load ch0, write buf0, start loading ch1.
    {
        const float4* src4 = (const float4*)chan_base;
        pre[0] = src4[tid];
        int j1 = tid + 512;
        pre[1] = src4[j1 < 900 ? j1 : 899];

        // write ch0 -> buf[0]
        {
            int row = tid / 15, c4 = tid - row * 15;
            *(float4*)&buf[0][row * TS + c4 * 4] = pre[0];
            if (j1 < 900) {
                int r1 = j1 / 15, c1 = j1 - r1 * 15;
                *(float4*)&buf[0][r1 * TS + c1 * 4] = pre[1];
            }
        }
        // load ch1 -> pre
        const float4* s1 = (const float4*)(chan_base + (size_t)(HIN * WIN));
        pre[0] = s1[tid];
        pre[1] = s1[(tid + 512) < 900 ? (tid + 512) : 899];
    }
    __syncthreads();

    const int cV = wc + EP;               // V-pass column (2..57), always valid

#pragma unroll 1
    for (int k = 0; k < NK; ++k) {
        const float* __restrict__ bf = buf[k & 1];

        const int c = co * NK + k;
        // Block-uniform per-channel shifts & weights
        int ph[GRP], pv[GRP];
        float a1[GRP], a2[GRP];
#pragma unroll
        for (int g = 0; g < GRP; ++g) {
            ph[g] = pad_hv[c * 8 + g];
            pv[g] = pad_hv[c * 8 + 4 + g];
            a1[g] = w1[g * C_IN_N + c];
            a2[g] = w2[g * C_IN_N + c];
        }
        float wi = 0.f;
#pragma unroll
        for (int g = 0; g < GRP; ++g)
            if (kI[g] == k) wi += w3v[g];

        // ---- H pass: row = h0+i+EP (always in [2,57]); col clamped+masked.
#pragma unroll
        for (int g = 0; g < GRP; ++g) {
            int ix  = wc + EP + ph[g];                 // may be OOB
            float wh = ((unsigned)ix < (unsigned)WIN) ? a1[g] : 0.f;
            int ixc = ix < 0 ? 0 : (ix > WIN - 1 ? WIN - 1 : ix);
#pragma unroll
            for (int i = 0; i < ROWS_PW; ++i)
                accH[i] = fmaf(bf[(h0 + i + EP) * TS + ixc], wh, accH[i]);
        }

        // ---- V pass: col = cV (valid); row clamped+masked per i.
#pragma unroll
        for (int g = 0; g < GRP; ++g) {
            const int rb = h0 + EP + pv[g];
#pragma unroll
            for (int i = 0; i < ROWS_PW; ++i) {
                int r   = rb + i;
                float wv = ((unsigned)r < (unsigned)HIN) ? a2[g] : 0.f;
                int rc  = r < 0 ? 0 : (r > HIN - 1 ? HIN - 1 : r);
                accV[i] = fmaf(bf[rc * TS + cV], wv, accV[i]);
            }
        }

        // ---- Identity pass (block-uniform branch)
        if (wi != 0.f) {
#pragma unroll
            for (int i = 0; i < ROWS_PW; ++i)
                accI[i] = fmaf(bf[(h0 + i + EP) * TS + cV], wi, accI[i]);
        }

        // ---- Pipeline: write prefetched ch(k+1) into other buffer,
        //      then start loading ch(k+2).
        if (k < NK - 1) {
            float* __restrict__ nb = buf[(k + 1) & 1];
            {
                int row = tid / 15, c4 = tid - row * 15;
                *(float4*)&nb[row * TS + c4 * 4] = pre[0];
                int j1 = tid + 512;
                if (j1 < 900) {
                    int r1 = j1 / 15, c1 = j1 - r1 * 15;
                    *(float4*)&nb[r1 * TS + c1 * 4] = pre[1];
                }
            }
            if (k < NK - 2) {
                const float4* sn = (const float4*)(chan_base + (size_t)(k + 2) * (HIN * WIN));
                pre[0] = sn[tid];
                pre[1] = sn[(tid + 512) < 900 ? (tid + 512) : 899];
            }
        }
        __syncthreads();   // next buffer ready; this buffer free for overwrite
    }

    // Epilogue: stores (rows are 224 B contiguous per lane-group; L2 combines).
    if (w < WOUT) {
        const size_t OSZ  = (size_t)BATCH * C_OUT_N * HOUT * WOUT;
        const size_t base = (((size_t)b * C_OUT_N + co) * HOUT + h0) * WOUT + w;
#pragma unroll
        for (int i = 0; i < ROWS_PW; ++i) {
            out[base + (size_t)i * WOUT]           = accH[i];
            out[OSZ + base + (size_t)i * WOUT]     = accV[i];
            out[2 * OSZ + base + (size_t)i * WOUT] = accI[i];
        }
    }
}

extern "C" void kernel_launch(void* const* d_in, const int* in_sizes, int n_in,
                              void* d_out, int out_size, void* d_ws, size_t ws_size,
                              hipStream_t stream) {
    const float* x   = (const float*)d_in[0];
    const float* w1  = (const float*)d_in[1];
    const float* w2  = (const float*)d_in[2];
    const float* w3  = (const float*)d_in[3];
    const int* pad_hv      = (const int*)d_in[4];
    const int* idx_identit = (const int*)d_in[5];
    float* out = (float*)d_out;

    dim3 grid(C_OUT_N, BATCH);   // 768 blocks, 512 threads = 24 waves/CU
    dim3 block(512);
    addshift_kernel<<<grid, block, 0, stream>>>(x, w1, w2, w3, pad_hv, idx_identit, out);
}

// Round 4
// 259.180 us; speedup vs baseline: 1.8979x; 1.8979x over previous
//
#include <hip/hip_runtime.h>

// Problem constants (fixed by the reference file)
#define BATCH   8
#define C_OUT_N 96
#define NK      11
#define C_IN_N  1056      // C_OUT_N * NK
#define GRP     4
#define HOUT    56
#define WOUT    56
#define HIN     60
#define WIN     60
#define EP      2

// Unpadded channel tile: 60 rows x 64-dword stride (cols 0..59 valid).
// OOB shift reads are handled by clamping the address and zeroing the weight,
// so no pad region is needed. 15360 B per buffer, double-buffered = 30720 B.
#define TS      64                // dwords per row (256 B)
#define TROWS   60
#define TILE_DW (TROWS * TS)      // 3840 dwords = 15360 B

#define ROWS_PW 7                 // rows per wave (8 waves x 7 = 56)

// One block per (b, co); 512 threads = 8 waves; double-buffered channels,
// ONE barrier per k. Grid 768 blocks -> 3 blocks/CU -> 24 waves/CU.
//
// NOTE on __launch_bounds__: measured on gfx950 (round 3) that the second
// argument behaves like CUDA's min-BLOCKS-per-CU, not waves-per-EU:
// (512,6) produced VGPR_Count=40 (= 2048-reg pool / 48 waves) and massive
// scratch spill traffic (FETCH 525 MB, WRITE 864 MB). (512,3) budgets
// 3 blocks * 8 waves = 24 waves/CU -> ~85 VGPR cap, enough for the ~65
// registers this kernel naturally needs.
__global__ __launch_bounds__(512, 3) void addshift_kernel(
    const float* __restrict__ x,
    const float* __restrict__ w1,
    const float* __restrict__ w2,
    const float* __restrict__ w3,
    const int*   __restrict__ pad_hv,       // (C_IN, 8)
    const int*   __restrict__ idx_identit,  // (C_OUT, 4)
    float* __restrict__ out)                // [out_h | out_v | out_i]
{
    const int co  = blockIdx.x;
    const int b   = blockIdx.y;
    const int tid = threadIdx.x;

    __shared__ __align__(16) float buf[2][TILE_DW];

    const int wave = tid >> 6;
    const int w    = tid & 63;
    const int wc   = (w < WOUT) ? w : (WOUT - 1);   // clamp idle lanes
    const int h0   = wave * ROWS_PW;

    // Block-uniform identity-gather info
    int   kI[GRP];
    float w3v[GRP];
#pragma unroll
    for (int g = 0; g < GRP; ++g) {
        kI[g]  = idx_identit[co * GRP + g] - co * NK;   // in [0, NK)
        w3v[g] = w3[g * C_OUT_N + co];
    }

    float accH[ROWS_PW], accV[ROWS_PW], accI[ROWS_PW];
#pragma unroll
    for (int i = 0; i < ROWS_PW; ++i) { accH[i] = 0.f; accV[i] = 0.f; accI[i] = 0.f; }

    const float* chan_base = x + ((size_t)b * C_IN_N + (size_t)co * NK) * (HIN * WIN);

    // Each channel = 900 float4; 512 threads -> 2 per thread (t=1 partial).
    float4 pre[2];

    // Prologue: load ch0, write buf0, start loading ch1.
    {
        const float4* src4 = (const float4*)chan_base;
        pre[0] = src4[tid];
        int j1 = tid + 512;
        pre[1] = src4[j1 < 900 ? j1 : 899];

        // write ch0 -> buf[0]
        {
            int row = tid / 15, c4 = tid - row * 15;
            *(float4*)&buf[0][row * TS + c4 * 4] = pre[0];
            if (j1 < 900) {
                int r1 = j1 / 15, c1 = j1 - r1 * 15;
                *(float4*)&buf[0][r1 * TS + c1 * 4] = pre[1];
            }
        }
        // load ch1 -> pre
        const float4* s1 = (const float4*)(chan_base + (size_t)(HIN * WIN));
        pre[0] = s1[tid];
        pre[1] = s1[(tid + 512) < 900 ? (tid + 512) : 899];
    }
    __syncthreads();

    const int cV = wc + EP;               // V-pass column (2..57), always valid

#pragma unroll 1
    for (int k = 0; k < NK; ++k) {
        const float* __restrict__ bf = buf[k & 1];

        const int c = co * NK + k;
        // Block-uniform per-channel shifts & weights
        int ph[GRP], pv[GRP];
        float a1[GRP], a2[GRP];
#pragma unroll
        for (int g = 0; g < GRP; ++g) {
            ph[g] = pad_hv[c * 8 + g];
            pv[g] = pad_hv[c * 8 + 4 + g];
            a1[g] = w1[g * C_IN_N + c];
            a2[g] = w2[g * C_IN_N + c];
        }
        float wi = 0.f;
#pragma unroll
        for (int g = 0; g < GRP; ++g)
            if (kI[g] == k) wi += w3v[g];

        // ---- H pass: row = h0+i+EP (always in [2,57]); col clamped+masked.
#pragma unroll
        for (int g = 0; g < GRP; ++g) {
            int ix  = wc + EP + ph[g];                 // may be OOB
            float wh = ((unsigned)ix < (unsigned)WIN) ? a1[g] : 0.f;
            int ixc = ix < 0 ? 0 : (ix > WIN - 1 ? WIN - 1 : ix);
#pragma unroll
            for (int i = 0; i < ROWS_PW; ++i)
                accH[i] = fmaf(bf[(h0 + i + EP) * TS + ixc], wh, accH[i]);
        }

        // ---- V pass: col = cV (valid); row clamped+masked per i.
#pragma unroll
        for (int g = 0; g < GRP; ++g) {
            const int rb = h0 + EP + pv[g];
#pragma unroll
            for (int i = 0; i < ROWS_PW; ++i) {
                int r   = rb + i;
                float wv = ((unsigned)r < (unsigned)HIN) ? a2[g] : 0.f;
                int rc  = r < 0 ? 0 : (r > HIN - 1 ? HIN - 1 : r);
                accV[i] = fmaf(bf[rc * TS + cV], wv, accV[i]);
            }
        }

        // ---- Identity pass (block-uniform branch)
        if (wi != 0.f) {
#pragma unroll
            for (int i = 0; i < ROWS_PW; ++i)
                accI[i] = fmaf(bf[(h0 + i + EP) * TS + cV], wi, accI[i]);
        }

        // ---- Pipeline: write prefetched ch(k+1) into other buffer,
        //      then start loading ch(k+2).
        if (k < NK - 1) {
            float* __restrict__ nb = buf[(k + 1) & 1];
            {
                int row = tid / 15, c4 = tid - row * 15;
                *(float4*)&nb[row * TS + c4 * 4] = pre[0];
                int j1 = tid + 512;
                if (j1 < 900) {
                    int r1 = j1 / 15, c1 = j1 - r1 * 15;
                    *(float4*)&nb[r1 * TS + c1 * 4] = pre[1];
                }
            }
            if (k < NK - 2) {
                const float4* sn = (const float4*)(chan_base + (size_t)(k + 2) * (HIN * WIN));
                pre[0] = sn[tid];
                pre[1] = sn[(tid + 512) < 900 ? (tid + 512) : 899];
            }
        }
        __syncthreads();   // next buffer ready; this buffer free for overwrite
    }

    // Epilogue: stores (rows are 224 B contiguous per lane-group; L2 combines).
    if (w < WOUT) {
        const size_t OSZ  = (size_t)BATCH * C_OUT_N * HOUT * WOUT;
        const size_t base = (((size_t)b * C_OUT_N + co) * HOUT + h0) * WOUT + w;
#pragma unroll
        for (int i = 0; i < ROWS_PW; ++i) {
            out[base + (size_t)i * WOUT]           = accH[i];
            out[OSZ + base + (size_t)i * WOUT]     = accV[i];
            out[2 * OSZ + base + (size_t)i * WOUT] = accI[i];
        }
    }
}

extern "C" void kernel_launch(void* const* d_in, const int* in_sizes, int n_in,
                              void* d_out, int out_size, void* d_ws, size_t ws_size,
                              hipStream_t stream) {
    const float* x   = (const float*)d_in[0];
    const float* w1  = (const float*)d_in[1];
    const float* w2  = (const float*)d_in[2];
    const float* w3  = (const float*)d_in[3];
    const int* pad_hv      = (const int*)d_in[4];
    const int* idx_identit = (const int*)d_in[5];
    float* out = (float*)d_out;

    dim3 grid(C_OUT_N, BATCH);   // 768 blocks, 512 threads = 24 waves/CU
    dim3 block(512);
    addshift_kernel<<<grid, block, 0, stream>>>(x, w1, w2, w3, pad_hv, idx_identit, out);
}

// Round 5
// 225.094 us; speedup vs baseline: 2.1853x; 1.1514x over previous
//
#include <hip/hip_runtime.h>

// Problem constants (fixed by the reference file)
#define BATCH   8
#define C_OUT_N 96
#define NK      11
#define C_IN_N  1056      // C_OUT_N * NK
#define GRP     4
#define HOUT    56
#define WOUT    56
#define HIN     60
#define WIN     60
#define EP      2

// Padded LDS tile (round-1 design): rows/cols cover all shifts [-29,21]
// -> row index ih+2+pad in [-27,78] = 106 rows; col pad 28 keeps 16B align.
// Unconditional reads: pad region stays zero, no mask/clamp VALU.
#define RPAD    27
#define CPADL   28
#define STRIDE  108               // dwords per padded row (432 B, 16B-aligned)
#define RTOT    106
#define TILE_DW (RTOT * STRIDE)   // 11448 dwords = 45792 B -> 3 blocks/CU

#define ROWS_PW 7                 // 8 waves x 7 rows = 56

// One block per (b, co); 512 threads = 8 waves; single padded tile,
// 2 barriers per k. Grid 768 = 3 blocks/CU -> 24 waves/CU (vs 12 in the
// 256-thread variant that measured 97.6 us latency-bound).
//
// __launch_bounds__ note (measured r3/r4): second arg acts like CUDA
// min-blocks-per-CU. (512,6) -> VGPR capped 40 -> spill catastrophe;
// (512,3) -> cap ~85, kernel used 68, no spill.
__global__ __launch_bounds__(512, 3) void addshift_kernel(
    const float* __restrict__ x,
    const float* __restrict__ w1,
    const float* __restrict__ w2,
    const float* __restrict__ w3,
    const int*   __restrict__ pad_hv,       // (C_IN, 8)
    const int*   __restrict__ idx_identit,  // (C_OUT, 4)
    float* __restrict__ out)                // [out_h | out_v | out_i]
{
    const int co  = blockIdx.x;
    const int b   = blockIdx.y;
    const int tid = threadIdx.x;

    __shared__ __align__(16) float tile[TILE_DW];

    // One-time zero clear (pads stay zero forever; interior overwritten per k).
    {
        const float4 z4 = {0.f, 0.f, 0.f, 0.f};
        for (int j = tid; j < TILE_DW / 4; j += 512)
            ((float4*)tile)[j] = z4;
    }

    const int wave = tid >> 6;
    const int w    = tid & 63;
    const int wc   = (w < WOUT) ? w : (WOUT - 1);   // clamp idle lanes' addrs
    const int h0   = wave * ROWS_PW;

    // Block-uniform identity-gather info
    int   kI[GRP];
    float w3v[GRP];
#pragma unroll
    for (int g = 0; g < GRP; ++g) {
        kI[g]  = idx_identit[co * GRP + g] - co * NK;   // in [0, NK)
        w3v[g] = w3[g * C_OUT_N + co];
    }

    float accH[ROWS_PW], accV[ROWS_PW], accI[ROWS_PW];
#pragma unroll
    for (int i = 0; i < ROWS_PW; ++i) { accH[i] = 0.f; accV[i] = 0.f; accI[i] = 0.f; }

    const float* chan_base = x + ((size_t)b * C_IN_N + (size_t)co * NK) * (HIN * WIN);

    // Channel = 900 float4; 512 threads -> 2 per thread (second partial).
    float4 pre[2];
    {
        const float4* src4 = (const float4*)chan_base;
        pre[0] = src4[tid];
        int j1 = tid + 512;
        pre[1] = src4[j1 < 900 ? j1 : 899];
    }

    __syncthreads();   // zero-clear complete before first interior write

    const int rowH = (h0 + EP + RPAD) * STRIDE;   // out_h / out_i base row
    const int colV = wc + EP + CPADL;             // fixed column index

#pragma unroll 1
    for (int k = 0; k < NK; ++k) {
        const int c = co * NK + k;
        // Hoist block-uniform param loads above the barrier: s_load latency
        // hides under staging-write + __syncthreads.
        int ph[GRP], pv[GRP];
        float a1[GRP], a2[GRP];
#pragma unroll
        for (int g = 0; g < GRP; ++g) {
            ph[g] = pad_hv[c * 8 + g];
            pv[g] = pad_hv[c * 8 + 4 + g];
            a1[g] = w1[g * C_IN_N + c];
            a2[g] = w2[g * C_IN_N + c];
        }
        float wi = 0.f;
#pragma unroll
        for (int g = 0; g < GRP; ++g)
            if (kI[g] == k) wi += w3v[g];

        // regs -> LDS interior
        {
            int row = tid / 15, c4 = tid - row * 15;
            *(float4*)&tile[(row + RPAD) * STRIDE + CPADL + c4 * 4] = pre[0];
            int j1 = tid + 512;
            if (j1 < 900) {
                int r1 = j1 / 15, c1 = j1 - r1 * 15;
                *(float4*)&tile[(r1 + RPAD) * STRIDE + CPADL + c1 * 4] = pre[1];
            }
        }
        __syncthreads();

        // Prefetch next channel while this one computes
        if (k < NK - 1) {
            const float4* src4 = (const float4*)(chan_base + (size_t)(k + 1) * (HIN * WIN));
            pre[0] = src4[tid];
            int j1 = tid + 512;
            pre[1] = src4[j1 < 900 ? j1 : 899];
        }

        // ---- compute: unconditional reads, constant i*STRIDE offsets
        // (mergeable into ds_read2_b32 by the backend).
#pragma unroll
        for (int g = 0; g < GRP; ++g) {
            const int offH = rowH + colV + ph[g];
            const int offV = (h0 + EP + pv[g] + RPAD) * STRIDE + colV;
#pragma unroll
            for (int i = 0; i < ROWS_PW; ++i) {
                accH[i] = fmaf(tile[offH + i * STRIDE], a1[g], accH[i]);
                accV[i] = fmaf(tile[offV + i * STRIDE], a2[g], accV[i]);
            }
        }
        if (wi != 0.f) {                 // block-uniform branch
            const int offI = rowH + colV;
#pragma unroll
            for (int i = 0; i < ROWS_PW; ++i)
                accI[i] = fmaf(tile[offI + i * STRIDE], wi, accI[i]);
        }
        __syncthreads();   // tile reads done before next k's interior writes
    }

    // Epilogue: per-lane row stores (proven equivalent to slab stores in r2 A/B).
    if (w < WOUT) {
        const size_t OSZ  = (size_t)BATCH * C_OUT_N * HOUT * WOUT;
        const size_t base = (((size_t)b * C_OUT_N + co) * HOUT + h0) * WOUT + w;
#pragma unroll
        for (int i = 0; i < ROWS_PW; ++i) {
            out[base + (size_t)i * WOUT]           = accH[i];
            out[OSZ + base + (size_t)i * WOUT]     = accV[i];
            out[2 * OSZ + base + (size_t)i * WOUT] = accI[i];
        }
    }
}

extern "C" void kernel_launch(void* const* d_in, const int* in_sizes, int n_in,
                              void* d_out, int out_size, void* d_ws, size_t ws_size,
                              hipStream_t stream) {
    const float* x   = (const float*)d_in[0];
    const float* w1  = (const float*)d_in[1];
    const float* w2  = (const float*)d_in[2];
    const float* w3  = (const float*)d_in[3];
    const int* pad_hv      = (const int*)d_in[4];
    const int* idx_identit = (const int*)d_in[5];
    float* out = (float*)d_out;

    dim3 grid(C_OUT_N, BATCH);   // 768 blocks, 512 threads -> 24 waves/CU
    dim3 block(512);
    addshift_kernel<<<grid, block, 0, stream>>>(x, w1, w2, w3, pad_hv, idx_identit, out);
}

// Round 7
// 198.630 us; speedup vs baseline: 2.4764x; 1.1332x over previous
//
#include <hip/hip_runtime.h>

// Problem constants (fixed by the reference file)
#define BATCH   8
#define C_OUT_N 96
#define NK      11
#define C_IN_N  1056      // C_OUT_N * NK
#define GRP     4
#define HOUT    56
#define WOUT    56
#define HIN     60
#define WIN     60
#define EP      2

#define CH_DW   (HIN * WIN)   // 3600 dwords per channel, contiguous
#define BUF_DW  3840          // 3600 + 240 pad for DMA tail lanes (never read)
#define ROWS_PW 7             // 8 waves x 7 rows = 56 output rows

// Address-space pointer types for global_load_lds
typedef const float __attribute__((address_space(1)))* gas1_t;
typedef float       __attribute__((address_space(3)))* las3_t;

// DMA one 3600-dword channel into LDS (linear, stride 60 rows).
// Per wave: issue0 covers float4 [wid*64, wid*64+63] (max 511 < 900),
// issue1 covers [512+wid*64, ...]; tail lanes clamp the GLOBAL src (per-lane
// src is allowed) and land in the 240-dword pad; wave 7's issue1 skipped
// (dest would exceed the buffer).
__device__ __forceinline__ void stage_chan(const float* src, float* dst, int tid)
{
    const int wid  = tid >> 6;
    const int lane = tid & 63;
    __builtin_amdgcn_global_load_lds((gas1_t)(src + (wid * 64 + lane) * 4),
                                     (las3_t)(dst + wid * 256), 16, 0, 0);
    if (wid < 7) {
        int f1 = 512 + wid * 64 + lane;
        if (f1 > 899) f1 = 899;                       // clamp src, dest -> pad
        __builtin_amdgcn_global_load_lds((gas1_t)(src + f1 * 4),
                                         (las3_t)(dst + 2048 + wid * 256), 16, 0, 0);
    }
}

// One block per (b, co); 512 threads = 8 waves; double-buffered unpadded
// channel tiles; ONE barrier per k (implicit vmcnt/lgkm drain in
// __syncthreads covers the DMA). OOB handling: H by per-g col clamp +
// weight mask; V by wave-uniform fast/slow row split (fast path keeps
// compile-time i*60 offsets -> ds_read2_b32 merging).
__global__ __launch_bounds__(512, 3) void addshift_kernel(
    const float* __restrict__ x,
    const float* __restrict__ w1,
    const float* __restrict__ w2,
    const float* __restrict__ w3,
    const int*   __restrict__ pad_hv,       // (C_IN, 8)
    const int*   __restrict__ idx_identit,  // (C_OUT, 4)
    float* __restrict__ out)                // [out_h | out_v | out_i]
{
    const int co  = blockIdx.x;
    const int b   = blockIdx.y;
    const int tid = threadIdx.x;

    __shared__ __align__(16) float buf[2][BUF_DW];   // 30720 B

    const int wave = tid >> 6;
    const int w    = tid & 63;
    const int wc   = (w < WOUT) ? w : (WOUT - 1);    // clamp idle lanes
    const int h0   = __builtin_amdgcn_readfirstlane(wave * ROWS_PW); // scalar
    const int cV   = wc + EP;                        // V/I column, always valid

    // Block-uniform identity-gather info
    int   kI[GRP];
    float w3v[GRP];
#pragma unroll
    for (int g = 0; g < GRP; ++g) {
        kI[g]  = idx_identit[co * GRP + g] - co * NK;   // in [0, NK)
        w3v[g] = w3[g * C_OUT_N + co];
    }

    float accH[ROWS_PW], accV[ROWS_PW], accI[ROWS_PW];
#pragma unroll
    for (int i = 0; i < ROWS_PW; ++i) { accH[i] = 0.f; accV[i] = 0.f; accI[i] = 0.f; }

    const float* chan_base = x + ((size_t)b * C_IN_N + (size_t)co * NK) * CH_DW;

    // Prologue: DMA channel 0 into buf0.
    stage_chan(chan_base, buf[0], tid);

#pragma unroll 1
    for (int k = 0; k < NK; ++k) {
        // Single barrier per k: compiler emits s_waitcnt vmcnt(0) lgkmcnt(0)
        // before s_barrier -> DMA of channel k complete in ALL waves, and all
        // waves are done reading the buffer we are about to re-stage.
        __syncthreads();

        if (k + 1 < NK)
            stage_chan(chan_base + (size_t)(k + 1) * CH_DW, buf[(k + 1) & 1], tid);

        const float* __restrict__ bf = buf[k & 1];

        const int c = co * NK + k;
        int ph[GRP], pv[GRP];
        float a1[GRP], a2[GRP];
#pragma unroll
        for (int g = 0; g < GRP; ++g) {
            ph[g] = pad_hv[c * 8 + g];
            pv[g] = pad_hv[c * 8 + 4 + g];
            a1[g] = w1[g * C_IN_N + c];
            a2[g] = w2[g * C_IN_N + c];
        }
        float wi = 0.f;
#pragma unroll
        for (int g = 0; g < GRP; ++g)
            if (kI[g] == k) wi += w3v[g];

        // ---- H pass: rows h0+i+EP always valid; col clamped + weight-masked.
        const float* hrow = bf + (h0 + EP) * WIN;
#pragma unroll
        for (int g = 0; g < GRP; ++g) {
            int ix   = wc + EP + ph[g];                       // may be OOB
            float wh = ((unsigned)ix < (unsigned)WIN) ? a1[g] : 0.f;
            int ixc  = ix < 0 ? 0 : (ix > WIN - 1 ? WIN - 1 : ix);
            const float* p = hrow + ixc;
#pragma unroll
            for (int i = 0; i < ROWS_PW; ++i)
                accH[i] = fmaf(p[i * WIN], wh, accH[i]);
        }

        // ---- V pass: col cV valid; rows rb..rb+6, wave-uniform fast/slow.
#pragma unroll
        for (int g = 0; g < GRP; ++g) {
            const int rb = h0 + EP + pv[g];                   // scalar
            if (rb >= 0 && rb <= HIN - ROWS_PW) {             // fast: all rows in
                const float* p = bf + rb * WIN + cV;
#pragma unroll
                for (int i = 0; i < ROWS_PW; ++i)
                    accV[i] = fmaf(p[i * WIN], a2[g], accV[i]);
            } else {                                          // edge waves only
#pragma unroll
                for (int i = 0; i < ROWS_PW; ++i) {
                    int r    = rb + i;
                    float wv = ((unsigned)r < (unsigned)HIN) ? a2[g] : 0.f;
                    int rc   = r < 0 ? 0 : (r > HIN - 1 ? HIN - 1 : r);
                    accV[i]  = fmaf(bf[rc * WIN + cV], wv, accV[i]);
                }
            }
        }

        // ---- Identity pass (block-uniform branch)
        if (wi != 0.f) {
            const float* p = bf + (h0 + EP) * WIN + cV;
#pragma unroll
            for (int i = 0; i < ROWS_PW; ++i)
                accI[i] = fmaf(p[i * WIN], wi, accI[i]);
        }
    }

    // Epilogue: per-lane row stores (slab-store A/B in r2 showed no diff).
    if (w < WOUT) {
        const size_t OSZ  = (size_t)BATCH * C_OUT_N * HOUT * WOUT;
        const size_t base = (((size_t)b * C_OUT_N + co) * HOUT + h0) * WOUT + w;
#pragma unroll
        for (int i = 0; i < ROWS_PW; ++i) {
            out[base + (size_t)i * WOUT]           = accH[i];
            out[OSZ + base + (size_t)i * WOUT]     = accV[i];
            out[2 * OSZ + base + (size_t)i * WOUT] = accI[i];
        }
    }
}

extern "C" void kernel_launch(void* const* d_in, const int* in_sizes, int n_in,
                              void* d_out, int out_size, void* d_ws, size_t ws_size,
                              hipStream_t stream) {
    const float* x   = (const float*)d_in[0];
    const float* w1  = (const float*)d_in[1];
    const float* w2  = (const float*)d_in[2];
    const float* w3  = (const float*)d_in[3];
    const int* pad_hv      = (const int*)d_in[4];
    const int* idx_identit = (const int*)d_in[5];
    float* out = (float*)d_out;

    dim3 grid(C_OUT_N, BATCH);   // 768 blocks, 512 threads
    dim3 block(512);
    addshift_kernel<<<grid, block, 0, stream>>>(x, w1, w2, w3, pad_hv, idx_identit, out);
}